// Round 3
// baseline (204.547 us; speedup 1.0000x reference)
//
#include <hip/hip_runtime.h>
#include <cmath>

#define TAPE_SZ 100000
#define N_SZ    50000
#define F_SZ    32
#define B_SZ    128
#define NGRP    8          // b-groups, one per XCD (blockIdx & 7 -> XCD round-robin)
#define GSUB    16         // b's per group: 100000 rows * 32 B = 3.2 MB -> fits 4 MiB XCD L2

// ---- hybrid split ----
#define NBV     64                         // mode-A n's per block
#define N_SPLIT 30016                      // n < N_SPLIT -> mode A (L2), rest -> mode B (L3)
#define NCHA    (N_SPLIT / NBV)            // 469 A-chunks
#define NB_B    16                         // mode-B n's per block
#define NBLK_B  ((N_SZ - N_SPLIT) / NB_B)  // 1249 B-blocks (exact)
#define NPER    157                        // periods: 4 octets = 3 A-octets + 1 B-octet
#define NMAIN   (NPER * 4 * 8)             // 5024 main blocks
#define NTAIL   512
#define TAIL_F4 1600000                    // 128 b * 12500 float4 tail elements

typedef float        f32x4 __attribute__((ext_vector_type(4)));
typedef unsigned int u32x4 __attribute__((ext_vector_type(4)));

// Manual round-to-nearest-even f32 -> bf16 bits.
static __device__ __forceinline__ unsigned short f32_to_bf16(float f) {
    unsigned int u = __float_as_uint(f);
    u = (u + 0x7fffu + ((u >> 16) & 1u)) >> 16;
    return (unsigned short)u;
}

// ---------------------------------------------------------------------------
// Transpose writing BOTH layouts:
//   outP[g][row][bsub]  (g=b/16, bsub=b%16)  -- L2-partitioned, 32-B rows
//   outF[row][b]                             -- full 256-B rows for L3 path
// ---------------------------------------------------------------------------
__global__ __launch_bounds__(256) void transpose_both(const float* __restrict__ in,
                                                      unsigned short* __restrict__ outP,
                                                      unsigned short* __restrict__ outF) {
    __shared__ float tile[32][129];
    const int x0 = blockIdx.x * 32;
    const int tx = threadIdx.x;       // tape-col 0..31
    const int ty = threadIdx.y;       // 0..7

    #pragma unroll
    for (int yy = ty; yy < B_SZ; yy += 8)
        tile[tx][yy] = in[(size_t)yy * TAPE_SZ + x0 + tx];
    __syncthreads();

    const int tid = ty * 32 + tx;
    {   // partitioned layout
        const int g = tid >> 5, l = tid & 31;
        unsigned short* dst = outP + ((size_t)g * TAPE_SZ + x0 + l) * GSUB;
        union { unsigned short u[8]; uint4 q; } p0, p1;
        #pragma unroll
        for (int k = 0; k < 8; ++k) {
            p0.u[k] = f32_to_bf16(tile[l][g * GSUB + k]);
            p1.u[k] = f32_to_bf16(tile[l][g * GSUB + 8 + k]);
        }
        *(uint4*)dst       = p0.q;
        *(uint4*)(dst + 8) = p1.q;
    }
    {   // full-row layout
        const int l = tid >> 3, o = tid & 7;
        unsigned short* dst = outF + (size_t)(x0 + l) * B_SZ + o * 8;
        union { unsigned short u[8]; uint4 q; } p0, p1;
        #pragma unroll
        for (int k = 0; k < 8; ++k) {
            p0.u[k] = f32_to_bf16(tile[l][o * 8 + k]);
            p1.u[k] = f32_to_bf16(tile[l][64 + o * 8 + k]);
        }
        *(uint4*)dst        = p0.q;
        *(uint4*)(dst + 64) = p1.q;
    }
}

// ---------------------------------------------------------------------------
// Hybrid gather: octet role = A (L2-partitioned, 60% of n) / B (L3 full-row,
// 40% of n, non-temporal loads) / tail copy. 3A:1B octet interleave keeps both
// substrates busy concurrently; g = blockIdx&7 preserves A's XCD affinity.
// ---------------------------------------------------------------------------
union SMem {
    struct {
        int2  iw[NBV][33];     // (tape idx, weight bits), pitch 33
        float bias[NBV];
        int   act[NBV];
        int   oidx[NBV];
    } a;                       // 17664 B
    float ax[GSUB][68];        // A epilogue x-stage, aliases iw (4352 B)
    struct {
        int   idx[NB_B][33];
        float w[NB_B][33];
        float x[NB_B][132];
        float bias[NB_B];
        int   act[NB_B];
        int   oidx[NB_B];
    } b;                       // 12864 B
};

__global__ __launch_bounds__(256) void gather_mm(const unsigned short* __restrict__ tapeP,
                                                 const unsigned short* __restrict__ tapeF,
                                                 const float* __restrict__ weights,
                                                 const float* __restrict__ bias,
                                                 const int*   __restrict__ in_idx,
                                                 const int*   __restrict__ out_idx,
                                                 const int*   __restrict__ act_type,
                                                 const float* __restrict__ tape,
                                                 float* __restrict__ out) {
    __shared__ SMem sm;
    const int tid = threadIdx.x;

    if (blockIdx.x >= NMAIN) {
        // ---- tail copy: columns [N_SZ, TAPE_SZ) survive into out ----
        const int stride = NTAIL * 256;
        for (int i = (blockIdx.x - NMAIN) * 256 + tid; i < TAIL_F4; i += stride) {
            const int bb = i / 12500;
            const int j = i - bb * 12500;
            const size_t off = (size_t)bb * (TAPE_SZ / 4) + (N_SZ / 4) + j;
            f32x4 v = __builtin_nontemporal_load((const f32x4*)tape + off);
            __builtin_nontemporal_store(v, (f32x4*)out + off);
        }
        return;
    }

    const int oct = blockIdx.x >> 3;
    const int g   = blockIdx.x & 7;
    const int po  = oct & 3;           // 0..2 = A, 3 = B
    const int ro  = oct >> 2;

    if (po < 3) {
        // =================== mode A: L2-partitioned ===================
        const int chunk = ro * 3 + po;
        if (chunk >= NCHA) return;
        const int n0 = chunk * NBV;

        for (int t = tid; t < NBV * 32; t += 256) {
            const int n = t >> 5, f = t & 31;
            sm.a.iw[n][f] = make_int2(in_idx[(size_t)n0 * 32 + t],
                                      __float_as_int(weights[(size_t)n0 * 32 + t]));
        }
        if (tid < NBV) {
            sm.a.bias[tid] = bias[n0 + tid];
            sm.a.act[tid]  = act_type[n0 + tid];
            sm.a.oidx[tid] = out_idx[n0 + tid];
        }
        __syncthreads();

        const int nl = tid >> 2;          // n_local 0..63
        const int q  = tid & 3;           // b-quad
        const unsigned short* tg = tapeP + (size_t)g * TAPE_SZ * GSUB + q * 4;

        float a0 = 0.f, a1 = 0.f, a2 = 0.f, a3 = 0.f;
        #pragma unroll
        for (int fo = 0; fo < 32; fo += 8) {
            int2 iw8[8];
            #pragma unroll
            for (int j = 0; j < 8; ++j) iw8[j] = sm.a.iw[nl][fo + j];
            uint2 q8[8];
            #pragma unroll
            for (int j = 0; j < 8; ++j)
                q8[j] = *(const uint2*)(tg + (size_t)iw8[j].x * GSUB);
            #pragma unroll
            for (int j = 0; j < 8; ++j) {
                const float w = __int_as_float(iw8[j].y);
                a0 = fmaf(__uint_as_float(q8[j].x << 16),         w, a0);
                a1 = fmaf(__uint_as_float(q8[j].x & 0xffff0000u), w, a1);
                a2 = fmaf(__uint_as_float(q8[j].y << 16),         w, a2);
                a3 = fmaf(__uint_as_float(q8[j].y & 0xffff0000u), w, a3);
            }
        }
        const float bz = sm.a.bias[nl];
        a0 += bz; a1 += bz; a2 += bz; a3 += bz;
        if (sm.a.act[nl] == 0) {
            a0 = fmaxf(a0, 0.f); a1 = fmaxf(a1, 0.f);
            a2 = fmaxf(a2, 0.f); a3 = fmaxf(a3, 0.f);
        } else {
            a0 = tanhf(a0); a1 = tanhf(a1); a2 = tanhf(a2); a3 = tanhf(a3);
        }
        __syncthreads();   // iw reads done before aliased ax writes

        {
            const int bs = q * 4;
            sm.ax[bs + 0][nl] = a0; sm.ax[bs + 1][nl] = a1;
            sm.ax[bs + 2][nl] = a2; sm.ax[bs + 3][nl] = a3;
        }
        __syncthreads();

        for (int idx = tid; idx < GSUB * 16; idx += 256) {
            const int bsub = idx >> 4, j4 = idx & 15;
            const int nq  = j4 * 4;
            const int oc0 = sm.a.oidx[nq];
            float* orow = out + (size_t)(g * GSUB + bsub) * TAPE_SZ;
            const bool consec = (sm.a.oidx[nq + 1] == oc0 + 1) &&
                                (sm.a.oidx[nq + 2] == oc0 + 2) &&
                                (sm.a.oidx[nq + 3] == oc0 + 3) && ((oc0 & 3) == 0);
            if (consec) {
                *(float4*)(orow + oc0) = make_float4(sm.ax[bsub][nq + 0], sm.ax[bsub][nq + 1],
                                                     sm.ax[bsub][nq + 2], sm.ax[bsub][nq + 3]);
            } else {
                #pragma unroll
                for (int c = 0; c < 4; ++c)
                    orow[sm.a.oidx[nq + c]] = sm.ax[bsub][nq + c];
            }
        }
        return;
    }

    // =================== mode B: full-row via L3 (non-temporal) ===================
    const int bidx = ro * 8 + g;
    if (bidx >= NBLK_B) return;
    const int n0 = N_SPLIT + bidx * NB_B;

    for (int t = tid; t < NB_B * 32; t += 256) {
        const int n = t >> 5, f = t & 31;
        sm.b.idx[n][f] = in_idx[(size_t)n0 * 32 + t];
        sm.b.w[n][f]   = weights[(size_t)n0 * 32 + t];
    }
    if (tid < NB_B) {
        sm.b.bias[tid] = bias[n0 + tid];
        sm.b.act[tid]  = act_type[n0 + tid];
        sm.b.oidx[tid] = out_idx[n0 + tid];
    }
    __syncthreads();

    const int nl = tid >> 4;              // n_local 0..15
    const int bx = tid & 15;              // b-octet: b = 8*bx .. 8*bx+7
    const unsigned short* tf = tapeF + bx * 8;
    float a0 = 0.f, a1 = 0.f, a2 = 0.f, a3 = 0.f, a4 = 0.f, a5 = 0.f, a6 = 0.f, a7 = 0.f;

    #pragma unroll
    for (int fo = 0; fo < 32; fo += 8) {
        int   i8[8]; float w8[8];
        #pragma unroll
        for (int j = 0; j < 8; ++j) { i8[j] = sm.b.idx[nl][fo + j]; w8[j] = sm.b.w[nl][fo + j]; }
        u32x4 q8[8];
        #pragma unroll
        for (int j = 0; j < 8; ++j)
            q8[j] = __builtin_nontemporal_load((const u32x4*)(tf + (size_t)i8[j] * B_SZ));
        #pragma unroll
        for (int j = 0; j < 8; ++j) {
            const float w = w8[j];
            a0 = fmaf(__uint_as_float(q8[j][0] << 16),         w, a0);
            a1 = fmaf(__uint_as_float(q8[j][0] & 0xffff0000u), w, a1);
            a2 = fmaf(__uint_as_float(q8[j][1] << 16),         w, a2);
            a3 = fmaf(__uint_as_float(q8[j][1] & 0xffff0000u), w, a3);
            a4 = fmaf(__uint_as_float(q8[j][2] << 16),         w, a4);
            a5 = fmaf(__uint_as_float(q8[j][2] & 0xffff0000u), w, a5);
            a6 = fmaf(__uint_as_float(q8[j][3] << 16),         w, a6);
            a7 = fmaf(__uint_as_float(q8[j][3] & 0xffff0000u), w, a7);
        }
    }

    const float bz = sm.b.bias[nl];
    a0 += bz; a1 += bz; a2 += bz; a3 += bz; a4 += bz; a5 += bz; a6 += bz; a7 += bz;
    if (sm.b.act[nl] == 0) {
        a0 = fmaxf(a0, 0.f); a1 = fmaxf(a1, 0.f); a2 = fmaxf(a2, 0.f); a3 = fmaxf(a3, 0.f);
        a4 = fmaxf(a4, 0.f); a5 = fmaxf(a5, 0.f); a6 = fmaxf(a6, 0.f); a7 = fmaxf(a7, 0.f);
    } else {
        a0 = tanhf(a0); a1 = tanhf(a1); a2 = tanhf(a2); a3 = tanhf(a3);
        a4 = tanhf(a4); a5 = tanhf(a5); a6 = tanhf(a6); a7 = tanhf(a7);
    }
    {
        const int b8 = bx * 8;
        sm.b.x[nl][b8 + 0] = a0; sm.b.x[nl][b8 + 1] = a1; sm.b.x[nl][b8 + 2] = a2; sm.b.x[nl][b8 + 3] = a3;
        sm.b.x[nl][b8 + 4] = a4; sm.b.x[nl][b8 + 5] = a5; sm.b.x[nl][b8 + 6] = a6; sm.b.x[nl][b8 + 7] = a7;
    }
    __syncthreads();

    const int g4 = tid >> 6;              // n-quad 0..3
    const int b0 = tid & 63;
    const int oc0 = sm.b.oidx[g4 * 4];
    const bool consec = (sm.b.oidx[g4 * 4 + 1] == oc0 + 1) &&
                        (sm.b.oidx[g4 * 4 + 2] == oc0 + 2) &&
                        (sm.b.oidx[g4 * 4 + 3] == oc0 + 3) && ((oc0 & 3) == 0);
    #pragma unroll
    for (int rep = 0; rep < 2; ++rep) {
        const int b = b0 + rep * 64;
        const float4 v = make_float4(sm.b.x[g4 * 4 + 0][b], sm.b.x[g4 * 4 + 1][b],
                                     sm.b.x[g4 * 4 + 2][b], sm.b.x[g4 * 4 + 3][b]);
        if (consec) {
            *(float4*)(out + (size_t)b * TAPE_SZ + oc0) = v;
        } else {
            out[(size_t)b * TAPE_SZ + sm.b.oidx[g4 * 4 + 0]] = v.x;
            out[(size_t)b * TAPE_SZ + sm.b.oidx[g4 * 4 + 1]] = v.y;
            out[(size_t)b * TAPE_SZ + sm.b.oidx[g4 * 4 + 2]] = v.z;
            out[(size_t)b * TAPE_SZ + sm.b.oidx[g4 * 4 + 3]] = v.w;
        }
    }
}

// ---------------------------------------------------------------------------
// Tier-2 fallback (ws in [25.6, 51.2) MB): R1's partitioned-only path (proven).
// ---------------------------------------------------------------------------
#define NBV2    64
#define NCHUNK2 ((N_SZ + NBV2 - 1) / NBV2)
#define NGATH2  (NCHUNK2 * NGRP)

__global__ __launch_bounds__(256) void transpose_part(const float* __restrict__ in,
                                                      unsigned short* __restrict__ outT) {
    __shared__ float tile[32][129];
    const int x0 = blockIdx.x * 32;
    const int tx = threadIdx.x, ty = threadIdx.y;
    #pragma unroll
    for (int yy = ty; yy < B_SZ; yy += 8)
        tile[tx][yy] = in[(size_t)yy * TAPE_SZ + x0 + tx];
    __syncthreads();
    const int tid = ty * 32 + tx;
    const int g = tid >> 5, l = tid & 31;
    unsigned short* dst = outT + ((size_t)g * TAPE_SZ + x0 + l) * GSUB;
    union { unsigned short u[8]; uint4 q; } p0, p1;
    #pragma unroll
    for (int k = 0; k < 8; ++k) {
        p0.u[k] = f32_to_bf16(tile[l][g * GSUB + k]);
        p1.u[k] = f32_to_bf16(tile[l][g * GSUB + 8 + k]);
    }
    *(uint4*)dst = p0.q; *(uint4*)(dst + 8) = p1.q;
}

__global__ __launch_bounds__(256, 8) void gather_mm_part(const unsigned short* __restrict__ tapeT,
                                                         const float* __restrict__ weights,
                                                         const float* __restrict__ bias,
                                                         const int*   __restrict__ in_idx,
                                                         const int*   __restrict__ out_idx,
                                                         const int*   __restrict__ act_type,
                                                         const float* __restrict__ tape,
                                                         float* __restrict__ out) {
    __shared__ int2  s_iw[NBV2][33];
    __shared__ float s_bias[NBV2];
    __shared__ int   s_act[NBV2];
    __shared__ int   s_oidx[NBV2];
    float (*s_x)[68] = (float (*)[68])&s_iw[0][0];
    const int tid = threadIdx.x;

    if (blockIdx.x >= NGATH2) {
        const float4* src = (const float4*)tape;
        float4*       dst = (float4*)out;
        const int stride = NTAIL * 256;
        for (int i = (blockIdx.x - NGATH2) * 256 + tid; i < TAIL_F4; i += stride) {
            const int b = i / 12500;
            const int j = i - b * 12500;
            const int off = b * (TAPE_SZ / 4) + (N_SZ / 4) + j;
            dst[off] = src[off];
        }
        return;
    }
    const int g = blockIdx.x & (NGRP - 1);
    const int chunk = blockIdx.x >> 3;
    const int n0 = chunk * NBV2;
    const int nend = min(NBV2, N_SZ - n0);

    for (int t = tid; t < nend * 32; t += 256) {
        const int n = t >> 5, f = t & 31;
        s_iw[n][f] = make_int2(in_idx[(size_t)n0 * 32 + t],
                               __float_as_int(weights[(size_t)n0 * 32 + t]));
    }
    if (tid < nend) {
        s_bias[tid] = bias[n0 + tid];
        s_act[tid]  = act_type[n0 + tid];
        s_oidx[tid] = out_idx[n0 + tid];
    }
    __syncthreads();

    const int nl = tid >> 2, q = tid & 3;
    const unsigned short* tg = tapeT + (size_t)g * TAPE_SZ * GSUB + q * 4;
    float a0 = 0.f, a1 = 0.f, a2 = 0.f, a3 = 0.f;
    if (nl < nend) {
        #pragma unroll
        for (int fo = 0; fo < 32; fo += 8) {
            int2 iw8[8];
            #pragma unroll
            for (int j = 0; j < 8; ++j) iw8[j] = s_iw[nl][fo + j];
            uint2 q8[8];
            #pragma unroll
            for (int j = 0; j < 8; ++j)
                q8[j] = *(const uint2*)(tg + (size_t)iw8[j].x * GSUB);
            #pragma unroll
            for (int j = 0; j < 8; ++j) {
                const float w = __int_as_float(iw8[j].y);
                a0 = fmaf(__uint_as_float(q8[j].x << 16),         w, a0);
                a1 = fmaf(__uint_as_float(q8[j].x & 0xffff0000u), w, a1);
                a2 = fmaf(__uint_as_float(q8[j].y << 16),         w, a2);
                a3 = fmaf(__uint_as_float(q8[j].y & 0xffff0000u), w, a3);
            }
        }
        const float bz = s_bias[nl];
        a0 += bz; a1 += bz; a2 += bz; a3 += bz;
        if (s_act[nl] == 0) {
            a0 = fmaxf(a0, 0.f); a1 = fmaxf(a1, 0.f);
            a2 = fmaxf(a2, 0.f); a3 = fmaxf(a3, 0.f);
        } else {
            a0 = tanhf(a0); a1 = tanhf(a1); a2 = tanhf(a2); a3 = tanhf(a3);
        }
    }
    __syncthreads();
    if (nl < nend) {
        const int bs = q * 4;
        s_x[bs + 0][nl] = a0; s_x[bs + 1][nl] = a1;
        s_x[bs + 2][nl] = a2; s_x[bs + 3][nl] = a3;
    }
    __syncthreads();
    const int quads = (nend + 3) >> 2;
    for (int idx = tid; idx < GSUB * quads; idx += 256) {
        int bsub, j4;
        if (nend == NBV2) { bsub = idx >> 4; j4 = idx & 15; }
        else              { bsub = idx / quads; j4 = idx - bsub * quads; }
        const int nq = j4 * 4;
        const int oc0 = s_oidx[nq];
        float* orow = out + (size_t)(g * GSUB + bsub) * TAPE_SZ;
        const bool consec = (nq + 3 < nend) &&
                            (s_oidx[nq + 1] == oc0 + 1) && (s_oidx[nq + 2] == oc0 + 2) &&
                            (s_oidx[nq + 3] == oc0 + 3) && ((oc0 & 3) == 0);
        if (consec) {
            *(float4*)(orow + oc0) = make_float4(s_x[bsub][nq + 0], s_x[bsub][nq + 1],
                                                 s_x[bsub][nq + 2], s_x[bsub][nq + 3]);
        } else {
            #pragma unroll
            for (int c = 0; c < 4; ++c)
                if (nq + c < nend) orow[s_oidx[nq + c]] = s_x[bsub][nq + c];
        }
    }
}

// ---------------------------------------------------------------------------
// Tier-3 fallback (tiny ws): direct uncoalesced gather. Correct, slow.
// ---------------------------------------------------------------------------
__global__ __launch_bounds__(128) void gather_fallback(const float* __restrict__ tape,
                                                       const float* __restrict__ weights,
                                                       const float* __restrict__ bias,
                                                       const int*   __restrict__ in_idx,
                                                       const int*   __restrict__ out_idx,
                                                       const int*   __restrict__ act_type,
                                                       float* __restrict__ out) {
    const int n = blockIdx.x;
    const int b = threadIdx.x;
    float acc = 0.f;
    for (int f = 0; f < F_SZ; ++f) {
        acc += tape[(size_t)b * TAPE_SZ + in_idx[(size_t)n * F_SZ + f]] *
               weights[(size_t)n * F_SZ + f];
    }
    acc += bias[n];
    acc = (act_type[n] == 0) ? fmaxf(acc, 0.f) : tanhf(acc);
    out[(size_t)b * TAPE_SZ + out_idx[n]] = acc;
}

__global__ __launch_bounds__(256) void copy_tail_fb(const float* __restrict__ tape,
                                                    float* __restrict__ out) {
    const int n4 = (TAPE_SZ - N_SZ) / 4;
    int i = blockIdx.x * blockDim.x + threadIdx.x;
    int b = blockIdx.y;
    if (i < n4) {
        const float4* src = (const float4*)(tape + (size_t)b * TAPE_SZ + N_SZ);
        float4*       dst = (float4*)(out  + (size_t)b * TAPE_SZ + N_SZ);
        dst[i] = src[i];
    }
}

extern "C" void kernel_launch(void* const* d_in, const int* in_sizes, int n_in,
                              void* d_out, int out_size, void* d_ws, size_t ws_size,
                              hipStream_t stream) {
    const float* tape    = (const float*)d_in[0];
    const float* weights = (const float*)d_in[1];
    const float* bias    = (const float*)d_in[2];
    const int*   in_idx  = (const int*)d_in[3];
    const int*   out_idx = (const int*)d_in[4];
    const int*   act     = (const int*)d_in[5];
    float*       out     = (float*)d_out;

    const size_t one = (size_t)TAPE_SZ * B_SZ * sizeof(unsigned short);   // 25.6 MB
    if (ws_size >= 2 * one) {
        unsigned short* tapeP = (unsigned short*)d_ws;
        unsigned short* tapeF = tapeP + (size_t)TAPE_SZ * B_SZ;
        transpose_both<<<dim3(TAPE_SZ / 32), dim3(32, 8), 0, stream>>>(tape, tapeP, tapeF);
        gather_mm<<<dim3(NMAIN + NTAIL), dim3(256), 0, stream>>>(
            tapeP, tapeF, weights, bias, in_idx, out_idx, act, tape, out);
    } else if (ws_size >= one) {
        unsigned short* tapeT = (unsigned short*)d_ws;
        transpose_part<<<dim3(TAPE_SZ / 32), dim3(32, 8), 0, stream>>>(tape, tapeT);
        gather_mm_part<<<dim3(NGATH2 + NTAIL), dim3(256), 0, stream>>>(
            tapeT, weights, bias, in_idx, out_idx, act, tape, out);
    } else {
        copy_tail_fb<<<dim3(((TAPE_SZ - N_SZ) / 4 + 255) / 256, B_SZ), 256, 0, stream>>>(tape, out);
        gather_fallback<<<dim3(N_SZ), 128, 0, stream>>>(
            tape, weights, bias, in_idx, out_idx, act, out);
    }
}

// Round 4
// 188.859 us; speedup vs baseline: 1.0831x; 1.0831x over previous
//
#include <hip/hip_runtime.h>
#include <cmath>

#define TAPE_SZ 100000
#define N_SZ    50000
#define F_SZ    32
#define B_SZ    128
#define NGRP    8          // b-groups, one per XCD (blockIdx & 7 -> XCD round-robin)
#define GSUB    16         // b's per group: 100000 rows * 32 B = 3.2 MB -> fits 4 MiB XCD L2
#define NBV     128        // n's per gather block (256 thr = 128 n x 2 halves)
#define NCHUNK  ((N_SZ + NBV - 1) / NBV)   // 391 (last chunk has 80 n's)
#define NGATHER (NCHUNK * NGRP)            // 3128
#define NTAIL   512
#define TAIL_F4 1600000    // 128 b * 12500 float4 tail elements

// Manual round-to-nearest-even f32 -> bf16 bits.
static __device__ __forceinline__ unsigned short f32_to_bf16(float f) {
    unsigned int u = __float_as_uint(f);
    u = (u + 0x7fffu + ((u >> 16) & 1u)) >> 16;
    return (unsigned short)u;
}

// ---------------------------------------------------------------------------
// Kernel A: transpose tape (B x TAPE fp32) -> tapeT in XCD-partitioned layout:
// tapeT[g][row][bsub], g=b/16, bsub=b%16, bf16. Row-segment = 32 B so each
// XCD's slice (TAPE*16 ushorts, 3.2 MB) is contiguous and L2-resident.
// ---------------------------------------------------------------------------
__global__ __launch_bounds__(256) void transpose_tape(const float* __restrict__ in,
                                                      unsigned short* __restrict__ outT) {
    __shared__ float tile[32][129];
    const int x0 = blockIdx.x * 32;
    const int tx = threadIdx.x;       // tape-col 0..31
    const int ty = threadIdx.y;       // 0..7

    #pragma unroll
    for (int yy = ty; yy < B_SZ; yy += 8)
        tile[tx][yy] = in[(size_t)yy * TAPE_SZ + x0 + tx];
    __syncthreads();

    const int tid = ty * 32 + tx;
    const int g = tid >> 5;           // b-group 0..7
    const int l = tid & 31;           // row within tile
    unsigned short* dst = outT + ((size_t)g * TAPE_SZ + x0 + l) * GSUB;
    union { unsigned short u[8]; uint4 q; } p0, p1;
    #pragma unroll
    for (int k = 0; k < 8; ++k) {
        p0.u[k] = f32_to_bf16(tile[l][g * GSUB + k]);
        p1.u[k] = f32_to_bf16(tile[l][g * GSUB + 8 + k]);
    }
    *(uint4*)dst       = p0.q;
    *(uint4*)(dst + 8) = p1.q;
}

// ---------------------------------------------------------------------------
// Kernel B: gather-matmul, XCD-partitioned, 16B-per-lane gather.
// TA model: gather cost ~ lane-request count = bytes/16B. Thread = (n_local,
// half): one dwordx4 (16 B = 8 bf16 b's) per (n,f); 8 accumulators.
// LDS: packed int2 (idx,weight) [128][33] = 33.8 KB; epilogue x-stage aliased
// over it (barrier-separated). ~35 KB -> 4 blocks/CU = 16 waves (enough: R1
// showed occupancy beyond ~12 waves is not the binding resource).
// Tail blocks (>= NGATHER) copy columns [N_SZ, TAPE_SZ) of tape into out.
// ---------------------------------------------------------------------------
union SMemA {
    struct {
        int2  iw[NBV][33];     // (.x = tape idx, .y = weight bits); pitch 33
        float bias[NBV];
        int   act[NBV];
        int   oidx[NBV];
    } a;                       // 35328 B
    float ax[GSUB][132];       // epilogue x-stage, aliases iw (8448 B)
};

__global__ __launch_bounds__(256, 4) void gather_mm(const unsigned short* __restrict__ tapeT,
                                                    const float* __restrict__ weights,
                                                    const float* __restrict__ bias,
                                                    const int*   __restrict__ in_idx,
                                                    const int*   __restrict__ out_idx,
                                                    const int*   __restrict__ act_type,
                                                    const float* __restrict__ tape,
                                                    float* __restrict__ out) {
    __shared__ SMemA sm;
    const int tid = threadIdx.x;

    if (blockIdx.x >= NGATHER) {
        // ---- tail copy: columns [N_SZ, TAPE_SZ) survive into out ----
        const float4* src = (const float4*)tape;
        float4*       dst = (float4*)out;
        const int stride = NTAIL * 256;
        for (int i = (blockIdx.x - NGATHER) * 256 + tid; i < TAIL_F4; i += stride) {
            const int b = i / 12500;              // const div -> magic mul
            const int j = i - b * 12500;
            const int off = b * (TAPE_SZ / 4) + (N_SZ / 4) + j;
            dst[off] = src[off];
        }
        return;
    }

    const int g     = blockIdx.x & (NGRP - 1);
    const int chunk = blockIdx.x >> 3;
    const int n0    = chunk * NBV;
    const int nend  = min(NBV, N_SZ - n0);

    for (int t = tid; t < nend * 32; t += 256) {
        const int n = t >> 5, f = t & 31;
        sm.a.iw[n][f] = make_int2(in_idx[(size_t)n0 * 32 + t],
                                  __float_as_int(weights[(size_t)n0 * 32 + t]));
    }
    if (tid < nend) {
        sm.a.bias[tid] = bias[n0 + tid];
        sm.a.act[tid]  = act_type[n0 + tid];
        sm.a.oidx[tid] = out_idx[n0 + tid];
    }
    __syncthreads();

    const int nl = tid >> 1;              // n_local 0..127
    const int h  = tid & 1;               // segment half: b_sub = 8h .. 8h+7
    const unsigned short* tg = tapeT + (size_t)g * TAPE_SZ * GSUB + h * 8;

    float a0 = 0.f, a1 = 0.f, a2 = 0.f, a3 = 0.f, a4 = 0.f, a5 = 0.f, a6 = 0.f, a7 = 0.f;
    if (nl < nend) {
        #pragma unroll
        for (int fo = 0; fo < 32; fo += 8) {
            int2 iw8[8];
            #pragma unroll
            for (int j = 0; j < 8; ++j) iw8[j] = sm.a.iw[nl][fo + j];
            uint4 q8[8];
            #pragma unroll
            for (int j = 0; j < 8; ++j)
                q8[j] = *(const uint4*)(tg + (size_t)iw8[j].x * GSUB);
            #pragma unroll
            for (int j = 0; j < 8; ++j) {
                const float w = __int_as_float(iw8[j].y);
                a0 = fmaf(__uint_as_float(q8[j].x << 16),         w, a0);
                a1 = fmaf(__uint_as_float(q8[j].x & 0xffff0000u), w, a1);
                a2 = fmaf(__uint_as_float(q8[j].y << 16),         w, a2);
                a3 = fmaf(__uint_as_float(q8[j].y & 0xffff0000u), w, a3);
                a4 = fmaf(__uint_as_float(q8[j].z << 16),         w, a4);
                a5 = fmaf(__uint_as_float(q8[j].z & 0xffff0000u), w, a5);
                a6 = fmaf(__uint_as_float(q8[j].w << 16),         w, a6);
                a7 = fmaf(__uint_as_float(q8[j].w & 0xffff0000u), w, a7);
            }
        }
        const float bz = sm.a.bias[nl];
        a0 += bz; a1 += bz; a2 += bz; a3 += bz; a4 += bz; a5 += bz; a6 += bz; a7 += bz;
        if (sm.a.act[nl] == 0) {
            a0 = fmaxf(a0, 0.f); a1 = fmaxf(a1, 0.f); a2 = fmaxf(a2, 0.f); a3 = fmaxf(a3, 0.f);
            a4 = fmaxf(a4, 0.f); a5 = fmaxf(a5, 0.f); a6 = fmaxf(a6, 0.f); a7 = fmaxf(a7, 0.f);
        } else {
            a0 = tanhf(a0); a1 = tanhf(a1); a2 = tanhf(a2); a3 = tanhf(a3);
            a4 = tanhf(a4); a5 = tanhf(a5); a6 = tanhf(a6); a7 = tanhf(a7);
        }
    }
    __syncthreads();   // all iw reads complete before aliased ax writes

    if (nl < nend) {
        const int bs = h * 8;
        sm.ax[bs + 0][nl] = a0; sm.ax[bs + 1][nl] = a1;
        sm.ax[bs + 2][nl] = a2; sm.ax[bs + 3][nl] = a3;
        sm.ax[bs + 4][nl] = a4; sm.ax[bs + 5][nl] = a5;
        sm.ax[bs + 6][nl] = a6; sm.ax[bs + 7][nl] = a7;
    }
    __syncthreads();

    // Epilogue: coalesced float4 row stores (out_idx consecutive in this
    // problem); scalar fallback otherwise.
    const int quads = (nend + 3) >> 2;
    for (int idx = tid; idx < GSUB * quads; idx += 256) {
        int bsub, j4;
        if (nend == NBV) { bsub = idx >> 5; j4 = idx & 31; }
        else             { bsub = idx / quads; j4 = idx - bsub * quads; }
        const int nq  = j4 * 4;
        const int oc0 = sm.a.oidx[nq];
        float* orow = out + (size_t)(g * GSUB + bsub) * TAPE_SZ;
        const bool consec = (nq + 3 < nend) &&
                            (sm.a.oidx[nq + 1] == oc0 + 1) &&
                            (sm.a.oidx[nq + 2] == oc0 + 2) &&
                            (sm.a.oidx[nq + 3] == oc0 + 3) && ((oc0 & 3) == 0);
        if (consec) {
            *(float4*)(orow + oc0) = make_float4(sm.ax[bsub][nq + 0], sm.ax[bsub][nq + 1],
                                                 sm.ax[bsub][nq + 2], sm.ax[bsub][nq + 3]);
        } else {
            #pragma unroll
            for (int c = 0; c < 4; ++c)
                if (nq + c < nend) orow[sm.ax ? sm.a.oidx[nq + c] : 0] = sm.ax[bsub][nq + c];
        }
    }
}

// ---------------------------------------------------------------------------
// Fallback (workspace too small): direct uncoalesced gather. Correct, slow.
// ---------------------------------------------------------------------------
__global__ __launch_bounds__(128) void gather_fallback(const float* __restrict__ tape,
                                                       const float* __restrict__ weights,
                                                       const float* __restrict__ bias,
                                                       const int*   __restrict__ in_idx,
                                                       const int*   __restrict__ out_idx,
                                                       const int*   __restrict__ act_type,
                                                       float* __restrict__ out) {
    const int n = blockIdx.x;
    const int b = threadIdx.x;
    float acc = 0.f;
    for (int f = 0; f < F_SZ; ++f) {
        acc += tape[(size_t)b * TAPE_SZ + in_idx[(size_t)n * F_SZ + f]] *
               weights[(size_t)n * F_SZ + f];
    }
    acc += bias[n];
    acc = (act_type[n] == 0) ? fmaxf(acc, 0.f) : tanhf(acc);
    out[(size_t)b * TAPE_SZ + out_idx[n]] = acc;
}

__global__ __launch_bounds__(256) void copy_tail_fb(const float* __restrict__ tape,
                                                    float* __restrict__ out) {
    const int n4 = (TAPE_SZ - N_SZ) / 4;
    int i = blockIdx.x * blockDim.x + threadIdx.x;
    int b = blockIdx.y;
    if (i < n4) {
        const float4* src = (const float4*)(tape + (size_t)b * TAPE_SZ + N_SZ);
        float4*       dst = (float4*)(out  + (size_t)b * TAPE_SZ + N_SZ);
        dst[i] = src[i];
    }
}

extern "C" void kernel_launch(void* const* d_in, const int* in_sizes, int n_in,
                              void* d_out, int out_size, void* d_ws, size_t ws_size,
                              hipStream_t stream) {
    const float* tape    = (const float*)d_in[0];
    const float* weights = (const float*)d_in[1];
    const float* bias    = (const float*)d_in[2];
    const int*   in_idx  = (const int*)d_in[3];
    const int*   out_idx = (const int*)d_in[4];
    const int*   act     = (const int*)d_in[5];
    float*       out     = (float*)d_out;

    const size_t need = (size_t)TAPE_SZ * B_SZ * sizeof(unsigned short);   // 25.6 MB
    if (ws_size >= need) {
        unsigned short* tapeT = (unsigned short*)d_ws;
        transpose_tape<<<dim3(TAPE_SZ / 32), dim3(32, 8), 0, stream>>>(tape, tapeT);
        gather_mm<<<dim3(NGATHER + NTAIL), dim3(256), 0, stream>>>(
            tapeT, weights, bias, in_idx, out_idx, act, tape, out);
    } else {
        copy_tail_fb<<<dim3(((TAPE_SZ - N_SZ) / 4 + 255) / 256, B_SZ), 256, 0, stream>>>(tape, out);
        gather_fallback<<<dim3(N_SZ), 128, 0, stream>>>(
            tape, weights, bias, in_idx, out_idx, act, out);
    }
}